// Round 9
// baseline (144.581 us; speedup 1.0000x reference)
//
#include <hip/hip_runtime.h>

// FeatureExpansion: per (b, ol) stride of 10x32 f32 -> 1120 f32 outputs
// [std(32) | z(32) | ld(32) | ret(32) | covf(496) | corrf(496)]
// One wave per stride-iteration; 4 waves per block; wave-local sync only.
// Persistent waves: each wave loops over ~20 strides with register prefetch
// (next stride's global loads issued before current stride's compute).
//
// HARD-WON RULE (R5/R6/R7 disasters, ~10x HBM traffic amplification):
// keep __launch_bounds__(256,4) AND keep LDS at 24,064 B/block (6 blocks/CU).
// Every configuration that reached 7-8 resident blocks/CU showed FETCH+WRITE
// blow up ~10x regardless of store structure. Do not slim LDS, do not raise
// the LB waves/EU arg.

typedef float fx4 __attribute__((ext_vector_type(4)));

constexpr int S      = 10;
constexpr int F      = 32;
constexpr int NPAIR  = 496;     // F*(F-1)/2
constexpr int OUTW   = 1120;    // 4*F + 2*NPAIR
constexpr int WAVES  = 4;
// per-wave LDS slice (floats): raw[320] | mu[32] | rs[32] | stage[1120]
constexpr int SLICE  = 320 + 64 + OUTW;   // 1504 floats = 6016 B; block = 24,064 B

// Wave-local barrier (each wave touches only its own LDS slice).
__device__ __forceinline__ void wave_sync() {
    asm volatile("s_waitcnt lgkmcnt(0)" ::: "memory");
    __builtin_amdgcn_sched_barrier(0);
}
__device__ __forceinline__ float fast_rcp(float x) { return __builtin_amdgcn_rcpf(x); }

__global__ __launch_bounds__(256, 4)
void fe_kernel(const float* __restrict__ in, float* __restrict__ out,
               int nstrides, int total_waves)
{
    __shared__ float lds[WAVES * SLICE];

    const int wv   = threadIdx.x >> 6;
    const int lane = threadIdx.x & 63;

    float* raw   = &lds[wv * SLICE];   // 10x32 raw tile
    float* muv   = raw + 320;          // mean per feature
    float* rsv   = raw + 352;          // rcp(std) per feature (0 where std==0)
    float* stage = raw + 384;          // 1120 packed outputs

    const int f    = lane & 31;
    const int half = lane >> 5;
    const int rb   = lane >> 3;   // 0..7
    const int cb   = lane & 7;    // 0..7

    int sid = blockIdx.x * WAVES + wv;
    if (sid >= nstrides) return;

    // ---- prologue: issue first stride's loads ----
    fx4 c0, c1;
    {
        const float* src = in + (size_t)sid * (S * F);
        c0 = __builtin_nontemporal_load((const fx4*)(src + 4 * lane));
        c1 = fx4{0.f, 0.f, 0.f, 0.f};
        if (lane < 16)
            c1 = __builtin_nontemporal_load((const fx4*)(src + 256 + 4 * lane));
    }

    while (sid < nstrides) {
        const int nsid = sid + total_waves;

        // ---- P1: registers -> LDS; then issue NEXT stride's global loads ----
        *(fx4*)(raw + 4 * lane) = c0;
        if (lane < 16) *(fx4*)(raw + 256 + 4 * lane) = c1;
        if (nsid < nstrides) {
            const float* nsrc = in + (size_t)nsid * (S * F);
            c0 = __builtin_nontemporal_load((const fx4*)(nsrc + 4 * lane));
            if (lane < 16)
                c1 = __builtin_nontemporal_load((const fx4*)(nsrc + 256 + 4 * lane));
        }
        wave_sync();

        // ---- P2: ONE 10-read pass -> mean, var (E[x^2]-mu^2), std, z, ld, ret ----
        {
            float sum = 0.f, sumsq = 0.f, ldacc = 0.f, first = 0.f, last = 0.f;
            #pragma unroll
            for (int s = 0; s < S; ++s) {
                float v = raw[s * F + f];          // halves read same addrs (broadcast)
                sum   += v;
                sumsq += v * v;
                ldacc += (float)(s + 1) * v;
                if (s == 0)     first = v;
                if (s == S - 1) last  = v;
            }
            if (half == 0) {
                float mean = sum * 0.1f;
                float var  = fmaxf(sumsq * 0.1f - mean * mean, 0.0f);  // biased var
                float sd   = __builtin_amdgcn_sqrtf(var);
                float rs   = (sd == 0.0f) ? 0.0f : fast_rcp(sd);
                muv[f] = mean;
                rsv[f] = rs;
                stage[f]     = sd;                // std
                stage[F + f] = mean * rs;         // z = divide_no_nan(mean, std)
            } else {
                stage[2 * F + f] = ldacc * (1.0f / 55.0f);               // linspace/55
                float ret = (first == 0.0f) ? 0.0f : last * fast_rcp(first);
                stage[3 * F + f] = ret - 1.0f;
            }
        }
        wave_sync();

        // ---- P5: pairwise products on RAW data; acc init = -10*mu_r*mu_c ----
        {
            fx4 ma = *(fx4*)(muv + 4 * rb);
            fx4 mb = *(fx4*)(muv + 4 * cb);
            fx4 ra = *(fx4*)(rsv + 4 * rb);
            fx4 rc = *(fx4*)(rsv + 4 * cb);
            const float maa[4] = {ma.x, ma.y, ma.z, ma.w};
            const float mbb[4] = {mb.x, mb.y, mb.z, mb.w};
            const float raa[4] = {ra.x, ra.y, ra.z, ra.w};
            const float rcc[4] = {rc.x, rc.y, rc.z, rc.w};

            float acc[4][4];
            #pragma unroll
            for (int i = 0; i < 4; ++i) {
                float nm = -10.0f * maa[i];
                #pragma unroll
                for (int j = 0; j < 4; ++j) acc[i][j] = nm * mbb[j];
            }

            #pragma unroll
            for (int s = 0; s < S; ++s) {
                fx4 a4 = *(fx4*)(raw + s * F + 4 * rb);   // 8 distinct addrs
                fx4 b4 = *(fx4*)(raw + s * F + 4 * cb);
                const float aa[4] = {a4.x, a4.y, a4.z, a4.w};
                const float bb[4] = {b4.x, b4.y, b4.z, b4.w};
                #pragma unroll
                for (int i = 0; i < 4; ++i)
                    #pragma unroll
                    for (int j = 0; j < 4; ++j)
                        acc[i][j] += aa[i] * bb[j];
            }

            #pragma unroll
            for (int i = 0; i < 4; ++i) {
                const int r = 4 * rb + i;
                #pragma unroll
                for (int j = 0; j < 4; ++j) {
                    const int c = 4 * cb + j;
                    if (r > c) {                        // strict lower triangle
                        const int p = (r * (r - 1)) / 2 + c;
                        float prod = acc[i][j];
                        stage[4 * F + p]         = prod * (1.0f / 9.0f);          // cov
                        stage[4 * F + NPAIR + p] = prod * 0.1f * raa[i] * rcc[j]; // corr
                    }
                }
            }
        }
        wave_sync();

        // ---- P6: coalesced streamed writeout: 280 float4 per stride ----
        {
            float* dst = out + (size_t)sid * OUTW;
            #pragma unroll
            for (int k = 0; k < 5; ++k) {
                int idx4 = lane + 64 * k;
                if (idx4 < OUTW / 4) {
                    fx4 v = *(fx4*)(stage + 4 * idx4);
                    __builtin_nontemporal_store(v, (fx4*)(dst + 4 * idx4));
                }
            }
        }
        wave_sync();   // stage ds_reads drained before next iteration overwrites

        sid = nsid;
    }
}

extern "C" void kernel_launch(void* const* d_in, const int* in_sizes, int n_in,
                              void* d_out, int out_size, void* d_ws, size_t ws_size,
                              hipStream_t stream)
{
    const float* in = (const float*)d_in[0];
    float* out      = (float*)d_out;
    const int nstrides = in_sizes[0] / (S * F);          // 122880
    // Persistent grid: 6 blocks/CU x 256 CU = 1536 blocks (matches the clean
    // 6-blocks/CU residency); each wave loops over ~20 strides.
    int blocks = 1536;
    const int max_blocks = (nstrides + WAVES - 1) / WAVES;
    if (blocks > max_blocks) blocks = max_blocks;
    const int total_waves = blocks * WAVES;
    fe_kernel<<<blocks, 256, 0, stream>>>(in, out, nstrides, total_waves);
}